// Round 12
// baseline (172.987 us; speedup 1.0000x reference)
//
#include <hip/hip_runtime.h>
#include <cstdint>

#define NEG 0.2f
#define SBSH 6
#define BNODES 64
#define CCAP 2400
#define EPT 5                  // ceil(CCAP/512)
#define CCHUNK 3328
#define CEPT 13
#define MAXNSB 1024
#define LOG2E 1.44269504088896f

typedef __attribute__((ext_vector_type(8))) short short8v;
typedef __attribute__((ext_vector_type(4))) float f32x4;

__device__ __forceinline__ unsigned short f2bf(float f) {
  unsigned u = __float_as_uint(f);
  return (unsigned short)((u + 0x7FFFu + ((u >> 16) & 1u)) >> 16);
}
__device__ __forceinline__ float bf2f(unsigned short h) {
  return __uint_as_float(((unsigned)h) << 16);
}

// ---- prep: W[k][c] f32 -> WtB[mat][c][k] bf16; qe[h] = 0.6*log2e*(att_h . We_h) ---
__global__ __launch_bounds__(256) void k_prep(const float* __restrict__ Wl,
    const float* __restrict__ Wr, const float* __restrict__ We,
    const float* __restrict__ att, unsigned short* __restrict__ WtB,
    float* __restrict__ qe) {
  int mat = blockIdx.x;
  const float* W = mat ? Wr : Wl;
  for (int i = threadIdx.x; i < 16384; i += 256) {
    int c = i >> 7, k = i & 127;
    WtB[mat * 16384 + c * 128 + k] = f2bf(W[k * 128 + c]);
  }
  if (mat == 0) {
    __shared__ float tmp[128];
    if (threadIdx.x < 128) tmp[threadIdx.x] = att[threadIdx.x] * We[threadIdx.x];
    __syncthreads();
    if (threadIdx.x < 4) {
      float s = 0.f;
      for (int c = 0; c < 32; ++c) s += tmp[threadIdx.x * 32 + c];
      qe[threadIdx.x] = 0.6f * LOG2E * s;
    }
  }
}

// ---- MFMA GEMM (swapped operands) + ql/qr epilogue dots --------------------------
__global__ __launch_bounds__(256) void k_gemm(const float* __restrict__ x,
    const unsigned short* __restrict__ WtB, const float* __restrict__ att,
    const float* __restrict__ bl, const float* __restrict__ br,
    unsigned short* __restrict__ xlb, unsigned short* __restrict__ xrb,
    float* __restrict__ ql, float* __restrict__ qr, int n) {
  __shared__ __align__(16) unsigned short xs[64][136];
  __shared__ __align__(16) unsigned short Wt[128][136];
  int tid = threadIdx.x;
  int B0 = blockIdx.x * 64;
  int mat = blockIdx.y;
  for (int i = tid; i < 64 * 32; i += 256) {
    int r = i >> 5, c4 = (i & 31) * 4;
    ushort4 o = {0, 0, 0, 0};
    if (B0 + r < n) {
      float4 v = *(const float4*)(x + (size_t)(B0 + r) * 128 + c4);
      o = make_ushort4(f2bf(v.x), f2bf(v.y), f2bf(v.z), f2bf(v.w));
    }
    *(ushort4*)&xs[r][c4] = o;
  }
  for (int i = tid; i < 128 * 32; i += 256) {
    int c = i >> 5, k4 = (i & 31) * 4;
    *(ushort4*)&Wt[c][k4] = *(const ushort4*)(WtB + (size_t)mat * 16384 + c * 128 + k4);
  }
  __syncthreads();
  int wv = tid >> 6, lane = tid & 63;
  int l15 = lane & 15, g = lane >> 4;
  int R0 = wv * 16;
  f32x4 acc[8];
  #pragma unroll
  for (int t = 0; t < 8; ++t) acc[t] = {0.f, 0.f, 0.f, 0.f};
  #pragma unroll
  for (int kc = 0; kc < 4; ++kc) {
    int k0 = kc * 32 + g * 8;
    short8v b = *(const short8v*)&xs[R0 + l15][k0];
    #pragma unroll
    for (int t = 0; t < 8; ++t) {
      short8v a = *(const short8v*)&Wt[t * 16 + l15][k0];
      acc[t] = __builtin_amdgcn_mfma_f32_16x16x32_bf16(a, b, acc[t], 0, 0, 0);
    }
  }
  const float* bias = mat ? br : bl;
  unsigned short* yp = mat ? xrb : xlb;
  float* qdst = mat ? qr : ql;
  int row = B0 + R0 + l15;
  float qp[4] = {0.f, 0.f, 0.f, 0.f};
  if (row < n) {
    const float s06 = 0.6f * LOG2E;
    #pragma unroll
    for (int t = 0; t < 8; ++t) {
      int c0 = t * 16 + g * 4;
      float4 bv = *(const float4*)(bias + c0);
      float4 av = *(const float4*)(att + c0);
      ushort4 o = {f2bf(acc[t][0] + bv.x), f2bf(acc[t][1] + bv.y),
                   f2bf(acc[t][2] + bv.z), f2bf(acc[t][3] + bv.w)};
      *(ushort4*)(yp + (size_t)row * 128 + c0) = o;
      float dot = av.x * bf2f(o.x) + av.y * bf2f(o.y)
                + av.z * bf2f(o.z) + av.w * bf2f(o.w);
      qp[t >> 1] += s06 * dot;
    }
  }
  #pragma unroll
  for (int h = 0; h < 4; ++h) {
    qp[h] += __shfl_xor(qp[h], 16);
    qp[h] += __shfl_xor(qp[h], 32);
  }
  if (row < n && g == 0)
    *(float4*)(qdst + (size_t)row * 4) = make_float4(qp[0], qp[1], qp[2], qp[3]);
}

// ---- coarse scatter into 64-node superbucket slabs -------------------------------
__global__ __launch_bounds__(256) void k_coarse(const int* __restrict__ eidx,
    const float* __restrict__ ew, unsigned* __restrict__ gsb,
    int2* __restrict__ csb, int E, int NSB) {
  __shared__ unsigned cnt[MAXNSB];
  __shared__ unsigned base[MAXNSB];
  int c0 = blockIdx.x * CCHUNK;
  int c1 = min(E, c0 + CCHUNK);
  if (c0 >= c1) return;
  for (int b = threadIdx.x; b < NSB; b += 256) cnt[b] = 0u;
  __syncthreads();
  unsigned dreg[CEPT];
  #pragma unroll
  for (int k = 0; k < CEPT; ++k) {
    int i = c0 + threadIdx.x + k * 256;
    unsigned d = 0u;
    if (i < c1) {
      d = (unsigned)eidx[E + i];
      atomicAdd(&cnt[d >> SBSH], 1u);
    }
    dreg[k] = d;
  }
  __syncthreads();
  for (int b = threadIdx.x; b < NSB; b += 256) {
    unsigned c = cnt[b];
    base[b] = c ? atomicAdd(&gsb[b], c) : 0u;
    cnt[b] = 0u;
  }
  __syncthreads();
  #pragma unroll
  for (int k = 0; k < CEPT; ++k) {
    int i = c0 + threadIdx.x + k * 256;
    if (i < c1) {
      unsigned d = dreg[k];
      unsigned b = d >> SBSH;
      unsigned slot = base[b] + atomicAdd(&cnt[b], 1u);
      if (slot < CCAP)
        csb[(size_t)b * CCAP + slot] =
            make_int2((eidx[i] << SBSH) | (int)(d & (BNODES - 1)), __float_as_int(ew[i]));
    }
  }
}

// ---- fused: 64-bin LDS counting-sort + softmax agg (decomposed leaky-dot) --------
__global__ __launch_bounds__(512) void k_agg(
    const unsigned* __restrict__ gsb, const int2* __restrict__ csb,
    const unsigned short* __restrict__ xlb, const unsigned short* __restrict__ xrb,
    const float* __restrict__ ql, const float* __restrict__ qr,
    const float* __restrict__ qe, const float* __restrict__ We,
    const float* __restrict__ att, const float* __restrict__ bias,
    float* __restrict__ out, int n) {
  __shared__ int2 es[CCAP];
  __shared__ unsigned rp[BNODES + 1];
  __shared__ unsigned cur[BNODES];
  __shared__ unsigned scnt[BNODES];
  int tid = threadIdx.x;
  int lane = tid & 63, wv = tid >> 6;
  int sb = blockIdx.x;
  int ne = min((int)gsb[sb], CCAP);
  const int2* srcp = csb + (size_t)sb * CCAP;
  if (tid < BNODES) scnt[tid] = 0u;
  __syncthreads();
  int2 er[EPT];
  #pragma unroll
  for (int k = 0; k < EPT; ++k) {
    int i = tid + k * 512;
    if (i < ne) {
      er[k] = srcp[i];
      atomicAdd(&scnt[er[k].x & (BNODES - 1)], 1u);
    }
  }
  __syncthreads();
  if (tid < 64) {
    unsigned s = scnt[lane];
    #pragma unroll
    for (int off = 1; off < 64; off <<= 1) {
      unsigned t = __shfl_up(s, off);
      if (lane >= off) s += t;
    }
    rp[lane + 1] = s;
    cur[lane] = 0u;
    if (lane == 0) rp[0] = 0u;
  }
  __syncthreads();
  #pragma unroll
  for (int k = 0; k < EPT; ++k) {
    int i = tid + k * 512;
    if (i < ne) {
      int dl = er[k].x & (BNODES - 1);
      unsigned slot = rp[dl] + atomicAdd(&cur[dl], 1u);
      es[slot] = make_int2(er[k].x >> SBSH, er[k].y);
    }
  }
  __syncthreads();

  int g = lane >> 4;          // edge-group 0..3
  int l4 = lane & 15;         // channel-lane
  int h = l4 >> 2;            // head
  int ch0 = l4 * 8;
  float4 weA = *(const float4*)(We + ch0);
  float4 weB = *(const float4*)(We + ch0 + 4);
  float4 atA = *(const float4*)(att + ch0);
  float4 atB = *(const float4*)(att + ch0 + 4);
  const float s04 = 0.4f * LOG2E;
  atA.x *= s04; atA.y *= s04; atA.z *= s04; atA.w *= s04;
  atB.x *= s04; atB.y *= s04; atB.z *= s04; atB.w *= s04;
  float qeh = qe[h];

  for (int dl = wv; dl < BNODES; dl += 8) {
    int d = (sb << SBSH) + dl;
    if (d >= n) break;
    int s0 = (int)rp[dl], s1 = (int)rp[dl + 1];
    uint4 xrq = *(const uint4*)(xrb + ((size_t)d << 7) + ch0);
    float4 xrA, xrB;
    xrA.x = __uint_as_float(xrq.x << 16);
    xrA.y = __uint_as_float(xrq.x & 0xFFFF0000u);
    xrA.z = __uint_as_float(xrq.y << 16);
    xrA.w = __uint_as_float(xrq.y & 0xFFFF0000u);
    xrB.x = __uint_as_float(xrq.z << 16);
    xrB.y = __uint_as_float(xrq.z & 0xFFFF0000u);
    xrB.z = __uint_as_float(xrq.w << 16);
    xrB.w = __uint_as_float(xrq.w & 0xFFFF0000u);
    float qrd = qr[(size_t)d * 4 + h];
    float den = 0.f, wmax = -INFINITY;
    float4 aA = {0, 0, 0, 0}, aB = {0, 0, 0, 0};
    int idx = s0 + g;
    bool valid = idx < s1;
    int2 ev = make_int2(0, 0);
    uint4 xq = {0, 0, 0, 0};
    float qls = 0.f;
    if (valid) {
      ev = es[idx];
      xq = *(const uint4*)(xlb + ((size_t)ev.x << 7) + ch0);
      qls = ql[(size_t)ev.x * 4 + h];
    }
    for (int j = s0; j < s1; j += 4) {
      int idxn = j + 4 + g;
      bool vn = idxn < s1;
      int2 evn = ev; uint4 xqn = xq; float qln = qls;
      if (vn) {
        evn = es[idxn];
        xqn = *(const uint4*)(xlb + ((size_t)evn.x << 7) + ch0);
        qln = ql[(size_t)evn.x * 4 + h];
      }
      if (valid) {
        float w = __int_as_float(ev.y);
        wmax = fmaxf(wmax, w);
        float4 xA, xB;
        xA.x = __uint_as_float(xq.x << 16);
        xA.y = __uint_as_float(xq.x & 0xFFFF0000u);
        xA.z = __uint_as_float(xq.y << 16);
        xA.w = __uint_as_float(xq.y & 0xFFFF0000u);
        xB.x = __uint_as_float(xq.z << 16);
        xB.y = __uint_as_float(xq.z & 0xFFFF0000u);
        xB.z = __uint_as_float(xq.w << 16);
        xB.w = __uint_as_float(xq.w & 0xFFFF0000u);
        float nl = 0.f, t;
        t = xA.x + fmaf(w, weA.x, xrA.x); nl = fmaf(atA.x, fabsf(t), nl);
        t = xA.y + fmaf(w, weA.y, xrA.y); nl = fmaf(atA.y, fabsf(t), nl);
        t = xA.z + fmaf(w, weA.z, xrA.z); nl = fmaf(atA.z, fabsf(t), nl);
        t = xA.w + fmaf(w, weA.w, xrA.w); nl = fmaf(atA.w, fabsf(t), nl);
        t = xB.x + fmaf(w, weB.x, xrB.x); nl = fmaf(atB.x, fabsf(t), nl);
        t = xB.y + fmaf(w, weB.y, xrB.y); nl = fmaf(atB.y, fabsf(t), nl);
        t = xB.z + fmaf(w, weB.z, xrB.z); nl = fmaf(atB.z, fabsf(t), nl);
        t = xB.w + fmaf(w, weB.w, xrB.w); nl = fmaf(atB.w, fabsf(t), nl);
        nl += __shfl_xor(nl, 1);
        nl += __shfl_xor(nl, 2);
        float pe = __builtin_amdgcn_exp2f(qls + fmaf(w, qeh, qrd) + nl);
        den += pe;
        aA.x += pe * xA.x; aA.y += pe * xA.y; aA.z += pe * xA.z; aA.w += pe * xA.w;
        aB.x += pe * xB.x; aB.y += pe * xB.y; aB.z += pe * xB.z; aB.w += pe * xB.w;
      }
      ev = evn; xq = xqn; qls = qln; valid = vn;
    }
    #pragma unroll
    for (int mask = 16; mask <= 32; mask <<= 1) {
      den += __shfl_xor(den, mask);
      aA.x += __shfl_xor(aA.x, mask); aA.y += __shfl_xor(aA.y, mask);
      aA.z += __shfl_xor(aA.z, mask); aA.w += __shfl_xor(aA.w, mask);
      aB.x += __shfl_xor(aB.x, mask); aB.y += __shfl_xor(aB.y, mask);
      aB.z += __shfl_xor(aB.z, mask); aB.w += __shfl_xor(aB.w, mask);
      wmax = fmaxf(wmax, __shfl_xor(wmax, mask));
    }
    // self-loop: weight = max incoming edge weight (0 if none)
    {
      float wl = (wmax > -INFINITY) ? wmax : 0.f;
      uint4 xq2 = *(const uint4*)(xlb + ((size_t)d << 7) + ch0);
      float4 xA, xB;
      xA.x = __uint_as_float(xq2.x << 16);
      xA.y = __uint_as_float(xq2.x & 0xFFFF0000u);
      xA.z = __uint_as_float(xq2.y << 16);
      xA.w = __uint_as_float(xq2.y & 0xFFFF0000u);
      xB.x = __uint_as_float(xq2.z << 16);
      xB.y = __uint_as_float(xq2.z & 0xFFFF0000u);
      xB.z = __uint_as_float(xq2.w << 16);
      xB.w = __uint_as_float(xq2.w & 0xFFFF0000u);
      float nl = 0.f, t;
      t = xA.x + fmaf(wl, weA.x, xrA.x); nl = fmaf(atA.x, fabsf(t), nl);
      t = xA.y + fmaf(wl, weA.y, xrA.y); nl = fmaf(atA.y, fabsf(t), nl);
      t = xA.z + fmaf(wl, weA.z, xrA.z); nl = fmaf(atA.z, fabsf(t), nl);
      t = xA.w + fmaf(wl, weA.w, xrA.w); nl = fmaf(atA.w, fabsf(t), nl);
      t = xB.x + fmaf(wl, weB.x, xrB.x); nl = fmaf(atB.x, fabsf(t), nl);
      t = xB.y + fmaf(wl, weB.y, xrB.y); nl = fmaf(atB.y, fabsf(t), nl);
      t = xB.z + fmaf(wl, weB.z, xrB.z); nl = fmaf(atB.z, fabsf(t), nl);
      t = xB.w + fmaf(wl, weB.w, xrB.w); nl = fmaf(atB.w, fabsf(t), nl);
      nl += __shfl_xor(nl, 1);
      nl += __shfl_xor(nl, 2);
      float qld = ql[(size_t)d * 4 + h];
      float pe = __builtin_amdgcn_exp2f(qld + fmaf(wl, qeh, qrd) + nl);
      den += pe;
      aA.x += pe * xA.x; aA.y += pe * xA.y; aA.z += pe * xA.z; aA.w += pe * xA.w;
      aB.x += pe * xB.x; aB.y += pe * xB.y; aB.z += pe * xB.z; aB.w += pe * xB.w;
    }
    if (g == 0) {
      float r = 1.0f / den;
      float4 bvA = *(const float4*)(bias + ch0);
      float4 bvB = *(const float4*)(bias + ch0 + 4);
      float* op = out + (size_t)d * 128 + ch0;
      float4 oA = {aA.x * r + bvA.x, aA.y * r + bvA.y, aA.z * r + bvA.z, aA.w * r + bvA.w};
      float4 oB = {aB.x * r + bvB.x, aB.y * r + bvB.y, aB.z * r + bvB.z, aB.w * r + bvB.w};
      *(float4*)op = oA;
      *(float4*)(op + 4) = oB;
    }
  }
}

extern "C" void kernel_launch(void* const* d_in, const int* in_sizes, int n_in,
                              void* d_out, int out_size, void* d_ws, size_t ws_size,
                              hipStream_t stream) {
  const float* x     = (const float*)d_in[0];
  const int*   eidx  = (const int*)d_in[1];
  const float* ew_in = (const float*)d_in[2];
  const float* Wl    = (const float*)d_in[3];
  const float* bl    = (const float*)d_in[4];
  const float* Wr    = (const float*)d_in[5];
  const float* br    = (const float*)d_in[6];
  const float* We    = (const float*)d_in[7];
  const float* att   = (const float*)d_in[8];
  const float* bias  = (const float*)d_in[9];
  float* out = (float*)d_out;

  const int N = in_sizes[0] / 128;
  const int E = in_sizes[2];
  const int NSB = (N + BNODES - 1) >> SBSH;

  char* ws = (char*)d_ws;
  size_t off = 0;
  auto alloc = [&](size_t bytes) {
    void* p = ws + off;
    off = (off + bytes + 255) & ~(size_t)255;
    return p;
  };
  int2* csb = (int2*)alloc((size_t)NSB * CCAP * 8);          // ~15 MB
  unsigned short* xlb = (unsigned short*)alloc((size_t)N * 128 * 2);
  unsigned short* xrb = (unsigned short*)alloc((size_t)N * 128 * 2);
  unsigned short* WtB = (unsigned short*)alloc(2 * 16384 * 2);
  float* ql = (float*)alloc((size_t)N * 4 * 4);
  float* qr = (float*)alloc((size_t)N * 4 * 4);
  float* qe = (float*)alloc(4 * 4);
  unsigned* gsb = (unsigned*)alloc((size_t)NSB * 4);

  hipMemsetAsync(gsb, 0, (size_t)NSB * 4, stream);

  k_prep<<<2, 256, 0, stream>>>(Wl, Wr, We, att, WtB, qe);

  int nblk = (E + CCHUNK - 1) / CCHUNK;
  k_coarse<<<nblk, 256, 0, stream>>>(eidx, ew_in, gsb, csb, E, NSB);

  k_gemm<<<dim3((N + 63) / 64, 2), 256, 0, stream>>>(x, WtB, att, bl, br, xlb, xrb, ql, qr, N);

  k_agg<<<NSB, 512, 0, stream>>>(gsb, csb, xlb, xrb, ql, qr, qe, We, att, bias, out, N);
}

// Round 13
// 162.850 us; speedup vs baseline: 1.0622x; 1.0622x over previous
//
#include <hip/hip_runtime.h>
#include <cstdint>

#define NEG 0.2f
#define BSH 4
#define BNODES 16
#define CAP 768
#define EPT 3
#define SBSH 9
#define SBN 512
#define CCAP 18000
#define CCHUNK 3328
#define CEPT 13
#define FSLICE 8
#define LOG2E 1.44269504088896f

typedef __attribute__((ext_vector_type(8))) short short8v;
typedef __attribute__((ext_vector_type(4))) float f32x4;
typedef __attribute__((ext_vector_type(2))) float f32x2;

__device__ __forceinline__ unsigned short f2bf(float f) {
  unsigned u = __float_as_uint(f);
  return (unsigned short)((u + 0x7FFFu + ((u >> 16) & 1u)) >> 16);
}
__device__ __forceinline__ float bf2f(unsigned short h) {
  return __uint_as_float(((unsigned)h) << 16);
}

// ---- prep: W[k][c] f32 -> WtB[mat][c][k] bf16; qe[h] = 0.6*log2e*(att_h . We_h) ---
__global__ __launch_bounds__(256) void k_prep(const float* __restrict__ Wl,
    const float* __restrict__ Wr, const float* __restrict__ We,
    const float* __restrict__ att, unsigned short* __restrict__ WtB,
    float* __restrict__ qe) {
  int mat = blockIdx.x;
  const float* W = mat ? Wr : Wl;
  for (int i = threadIdx.x; i < 16384; i += 256) {
    int c = i >> 7, k = i & 127;
    WtB[mat * 16384 + c * 128 + k] = f2bf(W[k * 128 + c]);
  }
  if (mat == 0) {
    __shared__ float tmp[128];
    if (threadIdx.x < 128) tmp[threadIdx.x] = att[threadIdx.x] * We[threadIdx.x];
    __syncthreads();
    if (threadIdx.x < 4) {
      float s = 0.f;
      for (int c = 0; c < 32; ++c) s += tmp[threadIdx.x * 32 + c];
      qe[threadIdx.x] = 0.6f * LOG2E * s;
    }
  }
}

// ---- MFMA GEMM (fused mats, swapped operands) + ql/qr epilogue dots --------------
__global__ __launch_bounds__(256) void k_gemm(const float* __restrict__ x,
    const unsigned short* __restrict__ WtB, const float* __restrict__ att,
    const float* __restrict__ bl, const float* __restrict__ br,
    unsigned short* __restrict__ xlb, unsigned short* __restrict__ xrb,
    float* __restrict__ ql, float* __restrict__ qr, int n) {
  __shared__ __align__(16) unsigned short xs[64][136];
  __shared__ __align__(16) unsigned short Wt[128][136];
  int tid = threadIdx.x;
  int B0 = blockIdx.x * 64;
  for (int i = tid; i < 64 * 32; i += 256) {
    int r = i >> 5, c4 = (i & 31) * 4;
    ushort4 o = {0, 0, 0, 0};
    if (B0 + r < n) {
      float4 v = *(const float4*)(x + (size_t)(B0 + r) * 128 + c4);
      o = make_ushort4(f2bf(v.x), f2bf(v.y), f2bf(v.z), f2bf(v.w));
    }
    *(ushort4*)&xs[r][c4] = o;
  }
  int wv = tid >> 6, lane = tid & 63;
  int l15 = lane & 15, g = lane >> 4;
  int R0 = wv * 16;
  int row = B0 + R0 + l15;
  for (int mat = 0; mat < 2; ++mat) {
    __syncthreads();   // xs staged (mat0) / previous-mat Wt reads done (mat1)
    for (int i = tid; i < 128 * 32; i += 256) {
      int c = i >> 5, k4 = (i & 31) * 4;
      *(ushort4*)&Wt[c][k4] = *(const ushort4*)(WtB + (size_t)mat * 16384 + c * 128 + k4);
    }
    __syncthreads();
    f32x4 acc[8];
    #pragma unroll
    for (int t = 0; t < 8; ++t) acc[t] = {0.f, 0.f, 0.f, 0.f};
    #pragma unroll
    for (int kc = 0; kc < 4; ++kc) {
      int k0 = kc * 32 + g * 8;
      short8v b = *(const short8v*)&xs[R0 + l15][k0];
      #pragma unroll
      for (int t = 0; t < 8; ++t) {
        short8v a = *(const short8v*)&Wt[t * 16 + l15][k0];
        acc[t] = __builtin_amdgcn_mfma_f32_16x16x32_bf16(a, b, acc[t], 0, 0, 0);
      }
    }
    const float* bias = mat ? br : bl;
    unsigned short* yp = mat ? xrb : xlb;
    float* qdst = mat ? qr : ql;
    float qp[4] = {0.f, 0.f, 0.f, 0.f};
    if (row < n) {
      const float s06 = 0.6f * LOG2E;
      #pragma unroll
      for (int t = 0; t < 8; ++t) {
        int c0 = t * 16 + g * 4;
        float4 bv = *(const float4*)(bias + c0);
        float4 av = *(const float4*)(att + c0);
        ushort4 o = {f2bf(acc[t][0] + bv.x), f2bf(acc[t][1] + bv.y),
                     f2bf(acc[t][2] + bv.z), f2bf(acc[t][3] + bv.w)};
        *(ushort4*)(yp + (size_t)row * 128 + c0) = o;
        float dot = av.x * bf2f(o.x) + av.y * bf2f(o.y)
                  + av.z * bf2f(o.z) + av.w * bf2f(o.w);
        qp[t >> 1] += s06 * dot;
      }
    }
    #pragma unroll
    for (int h = 0; h < 4; ++h) {
      qp[h] += __shfl_xor(qp[h], 16);
      qp[h] += __shfl_xor(qp[h], 32);
    }
    if (row < n && g == 0)
      *(float4*)(qdst + (size_t)row * 4) = make_float4(qp[0], qp[1], qp[2], qp[3]);
  }
}

// ---- phase A: coarse scatter into superbucket slabs ------------------------------
__global__ __launch_bounds__(256) void k_coarse(const int* __restrict__ eidx,
    const float* __restrict__ ew, unsigned* __restrict__ gsb,
    int2* __restrict__ csb, int E, int NSB) {
  __shared__ unsigned cnt[128];
  __shared__ unsigned base[128];
  int c0 = blockIdx.x * CCHUNK;
  int c1 = min(E, c0 + CCHUNK);
  if (c0 >= c1) return;
  for (int b = threadIdx.x; b < NSB; b += 256) cnt[b] = 0u;
  __syncthreads();
  unsigned dreg[CEPT];
  #pragma unroll
  for (int k = 0; k < CEPT; ++k) {
    int i = c0 + threadIdx.x + k * 256;
    unsigned d = 0u;
    if (i < c1) {
      d = (unsigned)eidx[E + i];
      atomicAdd(&cnt[d >> SBSH], 1u);
    }
    dreg[k] = d;
  }
  __syncthreads();
  for (int b = threadIdx.x; b < NSB; b += 256) {
    unsigned c = cnt[b];
    base[b] = c ? atomicAdd(&gsb[b], c) : 0u;
    cnt[b] = 0u;
  }
  __syncthreads();
  #pragma unroll
  for (int k = 0; k < CEPT; ++k) {
    int i = c0 + threadIdx.x + k * 256;
    if (i < c1) {
      unsigned d = dreg[k];
      unsigned b = d >> SBSH;
      unsigned slot = base[b] + atomicAdd(&cnt[b], 1u);
      if (slot < CCAP)
        csb[(size_t)b * CCAP + slot] =
            make_int2((eidx[i] << SBSH) | (int)(d & (SBN - 1)), __float_as_int(ew[i]));
    }
  }
}

// ---- phase B: sliced split into 32 fine-bucket slabs (global reserve on fcnt) ----
__global__ __launch_bounds__(256) void k_fine(const unsigned* __restrict__ gsb,
    const int2* __restrict__ csb, int2* __restrict__ ebkt,
    unsigned* __restrict__ fcnt, int NB) {
  __shared__ unsigned cnt[32];
  __shared__ unsigned base[32];
  int sb = blockIdx.x / FSLICE;
  int sl = blockIdx.x % FSLICE;
  int ne = min((int)gsb[sb], CCAP);
  int chunk = (ne + FSLICE - 1) / FSLICE;
  int i0 = sl * chunk, i1 = min(ne, i0 + chunk);
  if (i0 >= i1) return;
  const int2* src = csb + (size_t)sb * CCAP;
  if (threadIdx.x < 32) cnt[threadIdx.x] = 0u;
  __syncthreads();
  for (int i = i0 + threadIdx.x; i < i1; i += 256)
    atomicAdd(&cnt[(src[i].x >> 4) & 31], 1u);
  __syncthreads();
  if (threadIdx.x < 32) {
    unsigned c = cnt[threadIdx.x];
    base[threadIdx.x] = c ? atomicAdd(&fcnt[sb * 32 + (int)threadIdx.x], c) : 0u;
    cnt[threadIdx.x] = 0u;
  }
  __syncthreads();
  for (int i = i0 + threadIdx.x; i < i1; i += 256) {
    int2 e = src[i];
    int fb = (e.x >> 4) & 31;
    unsigned slot = base[fb] + atomicAdd(&cnt[fb], 1u);
    if (slot < CAP) {
      int packed = ((e.x >> SBSH) << 4) | (e.x & 15);
      ebkt[(size_t)(sb * 32 + fb) * CAP + slot] = make_int2(packed, e.y);
    }
  }
}

// ---- fused: LDS counting-sort + softmax agg (packed-f32 decomposed leaky-dot) ----
__global__ __launch_bounds__(256) void k_agg(
    const unsigned* __restrict__ fcnt, const int2* __restrict__ ebkt,
    const unsigned short* __restrict__ xlb, const unsigned short* __restrict__ xrb,
    const float* __restrict__ ql, const float* __restrict__ qr,
    const float* __restrict__ qe, const float* __restrict__ We,
    const float* __restrict__ att, const float* __restrict__ bias,
    float* __restrict__ out, int n) {
  __shared__ int2 es[CAP];
  __shared__ unsigned rp[BNODES + 1];
  __shared__ unsigned cur[BNODES];
  __shared__ unsigned scnt[BNODES];
  int tid = threadIdx.x;
  int lane = tid & 63, wv = tid >> 6;
  int bkt = blockIdx.x;
  int ne = min((int)fcnt[bkt], CAP);
  const int2* srcp = ebkt + (size_t)bkt * CAP;
  if (tid < BNODES) scnt[tid] = 0u;
  __syncthreads();
  int2 er[EPT];
  #pragma unroll
  for (int k = 0; k < EPT; ++k) {
    int i = tid + k * 256;
    if (i < ne) {
      er[k] = srcp[i];
      atomicAdd(&scnt[er[k].x & (BNODES - 1)], 1u);
    }
  }
  __syncthreads();
  if (tid < 64) {
    unsigned s = (lane < BNODES) ? scnt[lane] : 0u;
    #pragma unroll
    for (int off = 1; off < BNODES; off <<= 1) {
      unsigned t = __shfl_up(s, off);
      if (lane >= off) s += t;
    }
    if (lane < BNODES) { rp[lane + 1] = s; cur[lane] = 0u; }
    if (lane == 0) rp[0] = 0u;
  }
  __syncthreads();
  #pragma unroll
  for (int k = 0; k < EPT; ++k) {
    int i = tid + k * 256;
    if (i < ne) {
      int dl = er[k].x & (BNODES - 1);
      unsigned slot = rp[dl] + atomicAdd(&cur[dl], 1u);
      es[slot] = make_int2(er[k].x >> BSH, er[k].y);
    }
  }
  __syncthreads();

  int g = lane >> 4;          // edge-group 0..3
  int l4 = lane & 15;         // channel-lane
  int h = l4 >> 2;            // head
  int ch0 = l4 * 8;
  f32x2 we2[4], at2[4];
  {
    const float s04 = 0.4f * LOG2E;
    #pragma unroll
    for (int p = 0; p < 4; ++p) {
      float2 w = *(const float2*)(We + ch0 + p * 2);
      float2 a = *(const float2*)(att + ch0 + p * 2);
      we2[p] = (f32x2){w.x, w.y};
      at2[p] = (f32x2){s04 * a.x, s04 * a.y};
    }
  }
  float qeh = qe[h];

  for (int dl = wv; dl < BNODES; dl += 4) {
    int d = (bkt << BSH) + dl;
    if (d >= n) break;
    int s0 = (int)rp[dl], s1 = (int)rp[dl + 1];
    uint4 xrq = *(const uint4*)(xrb + ((size_t)d << 7) + ch0);
    f32x2 xr2[4];
    xr2[0] = (f32x2){__uint_as_float(xrq.x << 16), __uint_as_float(xrq.x & 0xFFFF0000u)};
    xr2[1] = (f32x2){__uint_as_float(xrq.y << 16), __uint_as_float(xrq.y & 0xFFFF0000u)};
    xr2[2] = (f32x2){__uint_as_float(xrq.z << 16), __uint_as_float(xrq.z & 0xFFFF0000u)};
    xr2[3] = (f32x2){__uint_as_float(xrq.w << 16), __uint_as_float(xrq.w & 0xFFFF0000u)};
    float qrd = qr[(size_t)d * 4 + h];
    float den = 0.f, wmax = -INFINITY;
    f32x2 a2[4];
    a2[0] = a2[1] = a2[2] = a2[3] = (f32x2){0.f, 0.f};
    int idx = s0 + g;
    bool valid = idx < s1;
    int2 ev = make_int2(0, 0);
    uint4 xq = {0, 0, 0, 0};
    float qls = 0.f;
    if (valid) {
      ev = es[idx];
      xq = *(const uint4*)(xlb + ((size_t)ev.x << 7) + ch0);
      qls = ql[(size_t)ev.x * 4 + h];
    }
    for (int j = s0; j < s1; j += 4) {
      int idxn = j + 4 + g;
      bool vn = idxn < s1;
      int2 evn = ev; uint4 xqn = xq; float qln = qls;
      if (vn) {
        evn = es[idxn];
        xqn = *(const uint4*)(xlb + ((size_t)evn.x << 7) + ch0);
        qln = ql[(size_t)evn.x * 4 + h];
      }
      if (valid) {
        float w = __int_as_float(ev.y);
        wmax = fmaxf(wmax, w);
        f32x2 w2 = (f32x2){w, w};
        f32x2 x2[4];
        x2[0] = (f32x2){__uint_as_float(xq.x << 16), __uint_as_float(xq.x & 0xFFFF0000u)};
        x2[1] = (f32x2){__uint_as_float(xq.y << 16), __uint_as_float(xq.y & 0xFFFF0000u)};
        x2[2] = (f32x2){__uint_as_float(xq.z << 16), __uint_as_float(xq.z & 0xFFFF0000u)};
        x2[3] = (f32x2){__uint_as_float(xq.w << 16), __uint_as_float(xq.w & 0xFFFF0000u)};
        f32x2 nl2 = (f32x2){0.f, 0.f};
        #pragma unroll
        for (int p = 0; p < 4; ++p) {
          f32x2 t2 = __builtin_elementwise_fma(w2, we2[p], xr2[p]) + x2[p];
          nl2 = __builtin_elementwise_fma(at2[p], __builtin_elementwise_abs(t2), nl2);
        }
        float nl = nl2.x + nl2.y;
        nl += __shfl_xor(nl, 1);
        nl += __shfl_xor(nl, 2);
        float pe = __builtin_amdgcn_exp2f(qls + fmaf(w, qeh, qrd) + nl);
        den += pe;
        f32x2 pe2 = (f32x2){pe, pe};
        #pragma unroll
        for (int p = 0; p < 4; ++p)
          a2[p] = __builtin_elementwise_fma(pe2, x2[p], a2[p]);
      }
      ev = evn; xq = xqn; qls = qln; valid = vn;
    }
    #pragma unroll
    for (int mask = 16; mask <= 32; mask <<= 1) {
      den += __shfl_xor(den, mask);
      #pragma unroll
      for (int p = 0; p < 4; ++p) {
        a2[p].x += __shfl_xor(a2[p].x, mask);
        a2[p].y += __shfl_xor(a2[p].y, mask);
      }
      wmax = fmaxf(wmax, __shfl_xor(wmax, mask));
    }
    // self-loop: weight = max incoming edge weight (0 if none)
    {
      float wl = (wmax > -INFINITY) ? wmax : 0.f;
      uint4 xq2 = *(const uint4*)(xlb + ((size_t)d << 7) + ch0);
      f32x2 w2 = (f32x2){wl, wl};
      f32x2 x2[4];
      x2[0] = (f32x2){__uint_as_float(xq2.x << 16), __uint_as_float(xq2.x & 0xFFFF0000u)};
      x2[1] = (f32x2){__uint_as_float(xq2.y << 16), __uint_as_float(xq2.y & 0xFFFF0000u)};
      x2[2] = (f32x2){__uint_as_float(xq2.z << 16), __uint_as_float(xq2.z & 0xFFFF0000u)};
      x2[3] = (f32x2){__uint_as_float(xq2.w << 16), __uint_as_float(xq2.w & 0xFFFF0000u)};
      f32x2 nl2 = (f32x2){0.f, 0.f};
      #pragma unroll
      for (int p = 0; p < 4; ++p) {
        f32x2 t2 = __builtin_elementwise_fma(w2, we2[p], xr2[p]) + x2[p];
        nl2 = __builtin_elementwise_fma(at2[p], __builtin_elementwise_abs(t2), nl2);
      }
      float nl = nl2.x + nl2.y;
      nl += __shfl_xor(nl, 1);
      nl += __shfl_xor(nl, 2);
      float qld = ql[(size_t)d * 4 + h];
      float pe = __builtin_amdgcn_exp2f(qld + fmaf(wl, qeh, qrd) + nl);
      den += pe;
      f32x2 pe2 = (f32x2){pe, pe};
      #pragma unroll
      for (int p = 0; p < 4; ++p)
        a2[p] = __builtin_elementwise_fma(pe2, x2[p], a2[p]);
    }
    if (g == 0) {
      float r = 1.0f / den;
      float4 bvA = *(const float4*)(bias + ch0);
      float4 bvB = *(const float4*)(bias + ch0 + 4);
      float* op = out + (size_t)d * 128 + ch0;
      float4 oA = {a2[0].x * r + bvA.x, a2[0].y * r + bvA.y,
                   a2[1].x * r + bvA.z, a2[1].y * r + bvA.w};
      float4 oB = {a2[2].x * r + bvB.x, a2[2].y * r + bvB.y,
                   a2[3].x * r + bvB.z, a2[3].y * r + bvB.w};
      *(float4*)op = oA;
      *(float4*)(op + 4) = oB;
    }
  }
}

extern "C" void kernel_launch(void* const* d_in, const int* in_sizes, int n_in,
                              void* d_out, int out_size, void* d_ws, size_t ws_size,
                              hipStream_t stream) {
  const float* x     = (const float*)d_in[0];
  const int*   eidx  = (const int*)d_in[1];
  const float* ew_in = (const float*)d_in[2];
  const float* Wl    = (const float*)d_in[3];
  const float* bl    = (const float*)d_in[4];
  const float* Wr    = (const float*)d_in[5];
  const float* br    = (const float*)d_in[6];
  const float* We    = (const float*)d_in[7];
  const float* att   = (const float*)d_in[8];
  const float* bias  = (const float*)d_in[9];
  float* out = (float*)d_out;

  const int N = in_sizes[0] / 128;
  const int E = in_sizes[2];
  const int NB = (N + BNODES - 1) >> BSH;
  const int NSB = (N + SBN - 1) >> SBSH;

  char* ws = (char*)d_ws;
  size_t off = 0;
  auto alloc = [&](size_t bytes) {
    void* p = ws + off;
    off = (off + bytes + 255) & ~(size_t)255;
    return p;
  };
  int2* ebkt = (int2*)alloc((size_t)NB * CAP * 8);
  // overlay: csb dead before gemm writes xlb/xrb over it
  size_t ov_start = off;
  unsigned short* xlb = (unsigned short*)alloc((size_t)N * 128 * 2);
  unsigned short* xrb = (unsigned short*)alloc((size_t)N * 128 * 2);
  int2* csb = (int2*)(ws + ov_start);   // NSB*CCAP*8 = 14.1 MB < 25.6 MB overlay
  unsigned short* WtB = (unsigned short*)alloc(2 * 16384 * 2);
  float* ql = (float*)alloc((size_t)N * 4 * 4);
  float* qr = (float*)alloc((size_t)N * 4 * 4);
  float* qe = (float*)alloc(4 * 4);
  unsigned* fcnt = (unsigned*)alloc((size_t)NB * 4);
  unsigned* gsb  = (unsigned*)alloc((size_t)NSB * 4);

  // zero fcnt..gsb in one memset (adjacent allocations)
  size_t z0 = (size_t)((char*)fcnt - ws);
  size_t z1 = (size_t)((char*)gsb - ws) + (size_t)NSB * 4;
  hipMemsetAsync(ws + z0, 0, z1 - z0, stream);

  k_prep<<<2, 256, 0, stream>>>(Wl, Wr, We, att, WtB, qe);

  int nblk = (E + CCHUNK - 1) / CCHUNK;
  k_coarse<<<nblk, 256, 0, stream>>>(eidx, ew_in, gsb, csb, E, NSB);

  k_fine<<<NSB * FSLICE, 256, 0, stream>>>(gsb, csb, ebkt, fcnt, NB);

  k_gemm<<<(N + 63) / 64, 256, 0, stream>>>(x, WtB, att, bl, br, xlb, xrb, ql, qr, N);

  k_agg<<<NB, 256, 0, stream>>>(fcnt, ebkt, xlb, xrb, ql, qr, qe, We, att, bias, out, N);
}

// Round 14
// 155.723 us; speedup vs baseline: 1.1109x; 1.0458x over previous
//
#include <hip/hip_runtime.h>
#include <cstdint>

#define NEG 0.2f
#define BSH 4
#define BNODES 16
#define CAP 768
#define EPT 3
#define SBSH 9
#define SBN 512
#define CCAP 18000
#define CCHUNK 3328
#define CEPT 13
#define FSLICE 8
#define LOG2E 1.44269504088896f

typedef __attribute__((ext_vector_type(8))) short short8v;
typedef __attribute__((ext_vector_type(4))) float f32x4;
typedef __attribute__((ext_vector_type(2))) float f32x2;

__device__ __forceinline__ unsigned short f2bf(float f) {
  unsigned u = __float_as_uint(f);
  return (unsigned short)((u + 0x7FFFu + ((u >> 16) & 1u)) >> 16);
}
__device__ __forceinline__ float bf2f(unsigned short h) {
  return __uint_as_float(((unsigned)h) << 16);
}

// ---- prep: W[k][c] f32 -> WtB[mat][c][k] bf16; qe[h] = 0.6*log2e*(att_h . We_h) ---
__global__ __launch_bounds__(256) void k_prep(const float* __restrict__ Wl,
    const float* __restrict__ Wr, const float* __restrict__ We,
    const float* __restrict__ att, unsigned short* __restrict__ WtB,
    float* __restrict__ qe) {
  int mat = blockIdx.x;
  const float* W = mat ? Wr : Wl;
  for (int i = threadIdx.x; i < 16384; i += 256) {
    int c = i >> 7, k = i & 127;
    WtB[mat * 16384 + c * 128 + k] = f2bf(W[k * 128 + c]);
  }
  if (mat == 0) {
    __shared__ float tmp[128];
    if (threadIdx.x < 128) tmp[threadIdx.x] = att[threadIdx.x] * We[threadIdx.x];
    __syncthreads();
    if (threadIdx.x < 4) {
      float s = 0.f;
      for (int c = 0; c < 32; ++c) s += tmp[threadIdx.x * 32 + c];
      qe[threadIdx.x] = 0.6f * LOG2E * s;
    }
  }
}

// ---- FUSED: coarse scatter (blocks [0,NC)) + MFMA GEMM (blocks [NC,NC+NG)) ------
// Independent work; coarse is memory/atomic-bound, gemm is MFMA/LDS-bound.
__global__ __launch_bounds__(256) void k_gc(
    const int* __restrict__ eidx, const float* __restrict__ ew,
    unsigned* __restrict__ gsb, int2* __restrict__ csb, int E, int NSB, int NC,
    const float* __restrict__ x, const unsigned short* __restrict__ WtB,
    const float* __restrict__ att, const float* __restrict__ bl,
    const float* __restrict__ br, unsigned short* __restrict__ xlb,
    unsigned short* __restrict__ xrb, float* __restrict__ ql,
    float* __restrict__ qr, int n) {
  __shared__ __align__(16) unsigned short xs[64][136];
  __shared__ __align__(16) unsigned short Wt[128][136];
  int tid = threadIdx.x;
  if ((int)blockIdx.x < NC) {
    // ---------------- coarse scatter ----------------
    unsigned* cnt = (unsigned*)&xs[0][0];
    unsigned* base = cnt + 128;
    int c0 = blockIdx.x * CCHUNK;
    int c1 = min(E, c0 + CCHUNK);
    if (c0 >= c1) return;
    for (int b = tid; b < NSB; b += 256) cnt[b] = 0u;
    __syncthreads();
    unsigned dreg[CEPT];
    #pragma unroll
    for (int k = 0; k < CEPT; ++k) {
      int i = c0 + tid + k * 256;
      unsigned d = 0u;
      if (i < c1) {
        d = (unsigned)eidx[E + i];
        atomicAdd(&cnt[d >> SBSH], 1u);
      }
      dreg[k] = d;
    }
    __syncthreads();
    for (int b = tid; b < NSB; b += 256) {
      unsigned c = cnt[b];
      base[b] = c ? atomicAdd(&gsb[b], c) : 0u;
      cnt[b] = 0u;
    }
    __syncthreads();
    #pragma unroll
    for (int k = 0; k < CEPT; ++k) {
      int i = c0 + tid + k * 256;
      if (i < c1) {
        unsigned d = dreg[k];
        unsigned b = d >> SBSH;
        unsigned slot = base[b] + atomicAdd(&cnt[b], 1u);
        if (slot < CCAP)
          csb[(size_t)b * CCAP + slot] =
              make_int2((eidx[i] << SBSH) | (int)(d & (SBN - 1)), __float_as_int(ew[i]));
      }
    }
    return;
  }
  // ---------------- MFMA GEMM (both mats; stage x once) ----------------
  int B0 = ((int)blockIdx.x - NC) * 64;
  for (int i = tid; i < 64 * 32; i += 256) {
    int r = i >> 5, c4 = (i & 31) * 4;
    ushort4 o = {0, 0, 0, 0};
    if (B0 + r < n) {
      float4 v = *(const float4*)(x + (size_t)(B0 + r) * 128 + c4);
      o = make_ushort4(f2bf(v.x), f2bf(v.y), f2bf(v.z), f2bf(v.w));
    }
    *(ushort4*)&xs[r][c4] = o;
  }
  int wv = tid >> 6, lane = tid & 63;
  int l15 = lane & 15, g = lane >> 4;
  int R0 = wv * 16;
  int row = B0 + R0 + l15;
  for (int mat = 0; mat < 2; ++mat) {
    __syncthreads();
    for (int i = tid; i < 128 * 32; i += 256) {
      int c = i >> 5, k4 = (i & 31) * 4;
      *(ushort4*)&Wt[c][k4] = *(const ushort4*)(WtB + (size_t)mat * 16384 + c * 128 + k4);
    }
    __syncthreads();
    f32x4 acc[8];
    #pragma unroll
    for (int t = 0; t < 8; ++t) acc[t] = {0.f, 0.f, 0.f, 0.f};
    #pragma unroll
    for (int kc = 0; kc < 4; ++kc) {
      int k0 = kc * 32 + g * 8;
      short8v b = *(const short8v*)&xs[R0 + l15][k0];
      #pragma unroll
      for (int t = 0; t < 8; ++t) {
        short8v a = *(const short8v*)&Wt[t * 16 + l15][k0];
        acc[t] = __builtin_amdgcn_mfma_f32_16x16x32_bf16(a, b, acc[t], 0, 0, 0);
      }
    }
    const float* bias = mat ? br : bl;
    unsigned short* yp = mat ? xrb : xlb;
    float* qdst = mat ? qr : ql;
    float qp[4] = {0.f, 0.f, 0.f, 0.f};
    if (row < n) {
      const float s06 = 0.6f * LOG2E;
      #pragma unroll
      for (int t = 0; t < 8; ++t) {
        int c0 = t * 16 + g * 4;
        float4 bv = *(const float4*)(bias + c0);
        float4 av = *(const float4*)(att + c0);
        ushort4 o = {f2bf(acc[t][0] + bv.x), f2bf(acc[t][1] + bv.y),
                     f2bf(acc[t][2] + bv.z), f2bf(acc[t][3] + bv.w)};
        *(ushort4*)(yp + (size_t)row * 128 + c0) = o;
        float dot = av.x * bf2f(o.x) + av.y * bf2f(o.y)
                  + av.z * bf2f(o.z) + av.w * bf2f(o.w);
        qp[t >> 1] += s06 * dot;
      }
    }
    #pragma unroll
    for (int h = 0; h < 4; ++h) {
      qp[h] += __shfl_xor(qp[h], 16);
      qp[h] += __shfl_xor(qp[h], 32);
    }
    if (row < n && g == 0)
      *(float4*)(qdst + (size_t)row * 4) = make_float4(qp[0], qp[1], qp[2], qp[3]);
  }
}

// ---- phase B: sliced split into 32 fine-bucket slabs (global reserve on fcnt) ----
__global__ __launch_bounds__(256) void k_fine(const unsigned* __restrict__ gsb,
    const int2* __restrict__ csb, int2* __restrict__ ebkt,
    unsigned* __restrict__ fcnt, int NB) {
  __shared__ unsigned cnt[32];
  __shared__ unsigned base[32];
  int sb = blockIdx.x / FSLICE;
  int sl = blockIdx.x % FSLICE;
  int ne = min((int)gsb[sb], CCAP);
  int chunk = (ne + FSLICE - 1) / FSLICE;
  int i0 = sl * chunk, i1 = min(ne, i0 + chunk);
  if (i0 >= i1) return;
  const int2* src = csb + (size_t)sb * CCAP;
  if (threadIdx.x < 32) cnt[threadIdx.x] = 0u;
  __syncthreads();
  for (int i = i0 + threadIdx.x; i < i1; i += 256)
    atomicAdd(&cnt[(src[i].x >> 4) & 31], 1u);
  __syncthreads();
  if (threadIdx.x < 32) {
    unsigned c = cnt[threadIdx.x];
    base[threadIdx.x] = c ? atomicAdd(&fcnt[sb * 32 + (int)threadIdx.x], c) : 0u;
    cnt[threadIdx.x] = 0u;
  }
  __syncthreads();
  for (int i = i0 + threadIdx.x; i < i1; i += 256) {
    int2 e = src[i];
    int fb = (e.x >> 4) & 31;
    unsigned slot = base[fb] + atomicAdd(&cnt[fb], 1u);
    if (slot < CAP) {
      int packed = ((e.x >> SBSH) << 4) | (e.x & 15);
      ebkt[(size_t)(sb * 32 + fb) * CAP + slot] = make_int2(packed, e.y);
    }
  }
}

// ---- fused: LDS counting-sort + softmax agg (2-deep prefetch pipeline) -----------
__global__ __launch_bounds__(256) void k_agg(
    const unsigned* __restrict__ fcnt, const int2* __restrict__ ebkt,
    const unsigned short* __restrict__ xlb, const unsigned short* __restrict__ xrb,
    const float* __restrict__ ql, const float* __restrict__ qr,
    const float* __restrict__ qe, const float* __restrict__ We,
    const float* __restrict__ att, const float* __restrict__ bias,
    float* __restrict__ out, int n) {
  __shared__ int2 es[CAP];
  __shared__ unsigned rp[BNODES + 1];
  __shared__ unsigned cur[BNODES];
  __shared__ unsigned scnt[BNODES];
  int tid = threadIdx.x;
  int lane = tid & 63, wv = tid >> 6;
  int bkt = blockIdx.x;
  int ne = min((int)fcnt[bkt], CAP);
  const int2* srcp = ebkt + (size_t)bkt * CAP;
  if (tid < BNODES) scnt[tid] = 0u;
  __syncthreads();
  int2 er[EPT];
  #pragma unroll
  for (int k = 0; k < EPT; ++k) {
    int i = tid + k * 256;
    if (i < ne) {
      er[k] = srcp[i];
      atomicAdd(&scnt[er[k].x & (BNODES - 1)], 1u);
    }
  }
  __syncthreads();
  if (tid < 64) {
    unsigned s = (lane < BNODES) ? scnt[lane] : 0u;
    #pragma unroll
    for (int off = 1; off < BNODES; off <<= 1) {
      unsigned t = __shfl_up(s, off);
      if (lane >= off) s += t;
    }
    if (lane < BNODES) { rp[lane + 1] = s; cur[lane] = 0u; }
    if (lane == 0) rp[0] = 0u;
  }
  __syncthreads();
  #pragma unroll
  for (int k = 0; k < EPT; ++k) {
    int i = tid + k * 256;
    if (i < ne) {
      int dl = er[k].x & (BNODES - 1);
      unsigned slot = rp[dl] + atomicAdd(&cur[dl], 1u);
      es[slot] = make_int2(er[k].x >> BSH, er[k].y);
    }
  }
  __syncthreads();

  int g = lane >> 4;          // edge-group 0..3
  int l4 = lane & 15;         // channel-lane
  int h = l4 >> 2;            // head
  int ch0 = l4 * 8;
  f32x2 we2[4], at2[4];
  {
    const float s04 = 0.4f * LOG2E;
    #pragma unroll
    for (int p = 0; p < 4; ++p) {
      float2 w = *(const float2*)(We + ch0 + p * 2);
      float2 a = *(const float2*)(att + ch0 + p * 2);
      we2[p] = (f32x2){w.x, w.y};
      at2[p] = (f32x2){s04 * a.x, s04 * a.y};
    }
  }
  float qeh = qe[h];

  for (int dl = wv; dl < BNODES; dl += 4) {
    int d = (bkt << BSH) + dl;
    if (d >= n) break;
    int s0 = (int)rp[dl], s1 = (int)rp[dl + 1];
    uint4 xrq = *(const uint4*)(xrb + ((size_t)d << 7) + ch0);
    f32x2 xr2[4];
    xr2[0] = (f32x2){__uint_as_float(xrq.x << 16), __uint_as_float(xrq.x & 0xFFFF0000u)};
    xr2[1] = (f32x2){__uint_as_float(xrq.y << 16), __uint_as_float(xrq.y & 0xFFFF0000u)};
    xr2[2] = (f32x2){__uint_as_float(xrq.z << 16), __uint_as_float(xrq.z & 0xFFFF0000u)};
    xr2[3] = (f32x2){__uint_as_float(xrq.w << 16), __uint_as_float(xrq.w & 0xFFFF0000u)};
    float qrd = qr[(size_t)d * 4 + h];
    float den = 0.f, wmax = -INFINITY;
    f32x2 a2[4];
    a2[0] = a2[1] = a2[2] = a2[3] = (f32x2){0.f, 0.f};
    // 2-deep software pipeline
    int i0 = s0 + g, i1 = s0 + 4 + g;
    bool v0 = i0 < s1, v1 = i1 < s1;
    int2 e0 = make_int2(0, 0), e1 = make_int2(0, 0);
    uint4 q0 = {0, 0, 0, 0}, q1 = {0, 0, 0, 0};
    float l0 = 0.f, l1 = 0.f;
    if (v0) {
      e0 = es[i0];
      q0 = *(const uint4*)(xlb + ((size_t)e0.x << 7) + ch0);
      l0 = ql[(size_t)e0.x * 4 + h];
    }
    if (v1) {
      e1 = es[i1];
      q1 = *(const uint4*)(xlb + ((size_t)e1.x << 7) + ch0);
      l1 = ql[(size_t)e1.x * 4 + h];
    }
    for (int j = s0; j < s1; j += 4) {
      int i2 = j + 8 + g;
      bool v2 = i2 < s1;
      int2 e2 = e0; uint4 q2 = q0; float l2 = l0;
      if (v2) {
        e2 = es[i2];
        q2 = *(const uint4*)(xlb + ((size_t)e2.x << 7) + ch0);
        l2 = ql[(size_t)e2.x * 4 + h];
      }
      if (v0) {
        float w = __int_as_float(e0.y);
        wmax = fmaxf(wmax, w);
        f32x2 w2 = (f32x2){w, w};
        f32x2 x2[4];
        x2[0] = (f32x2){__uint_as_float(q0.x << 16), __uint_as_float(q0.x & 0xFFFF0000u)};
        x2[1] = (f32x2){__uint_as_float(q0.y << 16), __uint_as_float(q0.y & 0xFFFF0000u)};
        x2[2] = (f32x2){__uint_as_float(q0.z << 16), __uint_as_float(q0.z & 0xFFFF0000u)};
        x2[3] = (f32x2){__uint_as_float(q0.w << 16), __uint_as_float(q0.w & 0xFFFF0000u)};
        f32x2 nl2 = (f32x2){0.f, 0.f};
        #pragma unroll
        for (int p = 0; p < 4; ++p) {
          f32x2 t2 = __builtin_elementwise_fma(w2, we2[p], xr2[p]) + x2[p];
          nl2 = __builtin_elementwise_fma(at2[p], __builtin_elementwise_abs(t2), nl2);
        }
        float nl = nl2.x + nl2.y;
        nl += __shfl_xor(nl, 1);
        nl += __shfl_xor(nl, 2);
        float pe = __builtin_amdgcn_exp2f(l0 + fmaf(w, qeh, qrd) + nl);
        den += pe;
        f32x2 pe2 = (f32x2){pe, pe};
        #pragma unroll
        for (int p = 0; p < 4; ++p)
          a2[p] = __builtin_elementwise_fma(pe2, x2[p], a2[p]);
      }
      e0 = e1; q0 = q1; l0 = l1; v0 = v1;
      e1 = e2; q1 = q2; l1 = l2; v1 = v2;
    }
    #pragma unroll
    for (int mask = 16; mask <= 32; mask <<= 1) {
      den += __shfl_xor(den, mask);
      #pragma unroll
      for (int p = 0; p < 4; ++p) {
        a2[p].x += __shfl_xor(a2[p].x, mask);
        a2[p].y += __shfl_xor(a2[p].y, mask);
      }
      wmax = fmaxf(wmax, __shfl_xor(wmax, mask));
    }
    // self-loop: weight = max incoming edge weight (0 if none)
    {
      float wl = (wmax > -INFINITY) ? wmax : 0.f;
      uint4 xq2 = *(const uint4*)(xlb + ((size_t)d << 7) + ch0);
      f32x2 w2 = (f32x2){wl, wl};
      f32x2 x2[4];
      x2[0] = (f32x2){__uint_as_float(xq2.x << 16), __uint_as_float(xq2.x & 0xFFFF0000u)};
      x2[1] = (f32x2){__uint_as_float(xq2.y << 16), __uint_as_float(xq2.y & 0xFFFF0000u)};
      x2[2] = (f32x2){__uint_as_float(xq2.z << 16), __uint_as_float(xq2.z & 0xFFFF0000u)};
      x2[3] = (f32x2){__uint_as_float(xq2.w << 16), __uint_as_float(xq2.w & 0xFFFF0000u)};
      f32x2 nl2 = (f32x2){0.f, 0.f};
      #pragma unroll
      for (int p = 0; p < 4; ++p) {
        f32x2 t2 = __builtin_elementwise_fma(w2, we2[p], xr2[p]) + x2[p];
        nl2 = __builtin_elementwise_fma(at2[p], __builtin_elementwise_abs(t2), nl2);
      }
      float nl = nl2.x + nl2.y;
      nl += __shfl_xor(nl, 1);
      nl += __shfl_xor(nl, 2);
      float qld = ql[(size_t)d * 4 + h];
      float pe = __builtin_amdgcn_exp2f(qld + fmaf(wl, qeh, qrd) + nl);
      den += pe;
      f32x2 pe2 = (f32x2){pe, pe};
      #pragma unroll
      for (int p = 0; p < 4; ++p)
        a2[p] = __builtin_elementwise_fma(pe2, x2[p], a2[p]);
    }
    if (g == 0) {
      float r = 1.0f / den;
      float4 bvA = *(const float4*)(bias + ch0);
      float4 bvB = *(const float4*)(bias + ch0 + 4);
      float* op = out + (size_t)d * 128 + ch0;
      float4 oA = {a2[0].x * r + bvA.x, a2[0].y * r + bvA.y,
                   a2[1].x * r + bvA.z, a2[1].y * r + bvA.w};
      float4 oB = {a2[2].x * r + bvB.x, a2[2].y * r + bvB.y,
                   a2[3].x * r + bvB.z, a2[3].y * r + bvB.w};
      *(float4*)op = oA;
      *(float4*)(op + 4) = oB;
    }
  }
}

extern "C" void kernel_launch(void* const* d_in, const int* in_sizes, int n_in,
                              void* d_out, int out_size, void* d_ws, size_t ws_size,
                              hipStream_t stream) {
  const float* x     = (const float*)d_in[0];
  const int*   eidx  = (const int*)d_in[1];
  const float* ew_in = (const float*)d_in[2];
  const float* Wl    = (const float*)d_in[3];
  const float* bl    = (const float*)d_in[4];
  const float* Wr    = (const float*)d_in[5];
  const float* br    = (const float*)d_in[6];
  const float* We    = (const float*)d_in[7];
  const float* att   = (const float*)d_in[8];
  const float* bias  = (const float*)d_in[9];
  float* out = (float*)d_out;

  const int N = in_sizes[0] / 128;
  const int E = in_sizes[2];
  const int NB = (N + BNODES - 1) >> BSH;
  const int NSB = (N + SBN - 1) >> SBSH;

  char* ws = (char*)d_ws;
  size_t off = 0;
  auto alloc = [&](size_t bytes) {
    void* p = ws + off;
    off = (off + bytes + 255) & ~(size_t)255;
    return p;
  };
  // no overlay: coarse (csb) and gemm (xlb/xrb) now run concurrently
  int2* ebkt = (int2*)alloc((size_t)NB * CAP * 8);           // 19.2 MB
  int2* csb  = (int2*)alloc((size_t)NSB * CCAP * 8);         // 14.1 MB
  unsigned short* xlb = (unsigned short*)alloc((size_t)N * 128 * 2);  // 12.8 MB
  unsigned short* xrb = (unsigned short*)alloc((size_t)N * 128 * 2);  // 12.8 MB
  unsigned short* WtB = (unsigned short*)alloc(2 * 16384 * 2);
  float* ql = (float*)alloc((size_t)N * 4 * 4);
  float* qr = (float*)alloc((size_t)N * 4 * 4);
  float* qe = (float*)alloc(4 * 4);
  unsigned* fcnt = (unsigned*)alloc((size_t)NB * 4);
  unsigned* gsb  = (unsigned*)alloc((size_t)NSB * 4);

  // zero fcnt..gsb in one memset (adjacent allocations)
  size_t z0 = (size_t)((char*)fcnt - ws);
  size_t z1 = (size_t)((char*)gsb - ws) + (size_t)NSB * 4;
  hipMemsetAsync(ws + z0, 0, z1 - z0, stream);

  k_prep<<<2, 256, 0, stream>>>(Wl, Wr, We, att, WtB, qe);

  int NC = (E + CCHUNK - 1) / CCHUNK;
  int NG = (N + 63) / 64;
  k_gc<<<NC + NG, 256, 0, stream>>>(eidx, ew_in, gsb, csb, E, NSB, NC,
                                    x, WtB, att, bl, br, xlb, xrb, ql, qr, N);

  k_fine<<<NSB * FSLICE, 256, 0, stream>>>(gsb, csb, ebkt, fcnt, NB);

  k_agg<<<NB, 256, 0, stream>>>(fcnt, ebkt, xlb, xrb, ql, qr, qe, We, att, bias, out, N);
}

// Round 15
// 143.791 us; speedup vs baseline: 1.2030x; 1.0830x over previous
//
#include <hip/hip_runtime.h>
#include <cstdint>

#define NEG 0.2f
#define BSH 4
#define BNODES 16
#define CAP 768
#define EPT 3
#define SBSH 9
#define SBN 512
#define CCAP 18000
#define CCHUNK 3328
#define CEPT 13
#define FSLICE 8
#define LOG2E 1.44269504088896f

typedef __attribute__((ext_vector_type(8))) short short8v;
typedef __attribute__((ext_vector_type(4))) float f32x4;
typedef __attribute__((ext_vector_type(2))) float f32x2;

__device__ __forceinline__ unsigned short f2bf(float f) {
  unsigned u = __float_as_uint(f);
  return (unsigned short)((u + 0x7FFFu + ((u >> 16) & 1u)) >> 16);
}
__device__ __forceinline__ float bf2f(unsigned short h) {
  return __uint_as_float(((unsigned)h) << 16);
}

// ---- prep: W transpose->bf16; qe; also zeroes fcnt (blk0) and gsb (blk1) ---------
__global__ __launch_bounds__(256) void k_prep(const float* __restrict__ Wl,
    const float* __restrict__ Wr, const float* __restrict__ We,
    const float* __restrict__ att, unsigned short* __restrict__ WtB,
    float* __restrict__ qe, unsigned* __restrict__ fcnt, int NB,
    unsigned* __restrict__ gsb, int NSB) {
  int mat = blockIdx.x;
  const float* W = mat ? Wr : Wl;
  if (mat == 0) {
    for (int i = threadIdx.x; i < NB; i += 256) fcnt[i] = 0u;
  } else {
    for (int i = threadIdx.x; i < NSB; i += 256) gsb[i] = 0u;
  }
  for (int i = threadIdx.x; i < 16384; i += 256) {
    int c = i >> 7, k = i & 127;
    WtB[mat * 16384 + c * 128 + k] = f2bf(W[k * 128 + c]);
  }
  if (mat == 0) {
    __shared__ float tmp[128];
    if (threadIdx.x < 128) tmp[threadIdx.x] = att[threadIdx.x] * We[threadIdx.x];
    __syncthreads();
    if (threadIdx.x < 4) {
      float s = 0.f;
      for (int c = 0; c < 32; ++c) s += tmp[threadIdx.x * 32 + c];
      qe[threadIdx.x] = 0.6f * LOG2E * s;
    }
  }
}

// ---- FUSED: coarse scatter (blocks [0,NC)) + MFMA GEMM (blocks [NC,NC+NG)) ------
__global__ __launch_bounds__(256) void k_gc(
    const int* __restrict__ eidx, const float* __restrict__ ew,
    unsigned* __restrict__ gsb, int2* __restrict__ csb, int E, int NSB, int NC,
    const float* __restrict__ x, const unsigned short* __restrict__ WtB,
    const float* __restrict__ att, const float* __restrict__ bl,
    const float* __restrict__ br, unsigned short* __restrict__ xlb,
    unsigned short* __restrict__ xrb, float* __restrict__ ql,
    float* __restrict__ qr, int n) {
  __shared__ __align__(16) unsigned short xs[64][136];
  __shared__ __align__(16) unsigned short Wt[128][136];
  int tid = threadIdx.x;
  if ((int)blockIdx.x < NC) {
    // ---------------- coarse scatter ----------------
    unsigned* cnt = (unsigned*)&xs[0][0];
    unsigned* base = cnt + 128;
    int c0 = blockIdx.x * CCHUNK;
    int c1 = min(E, c0 + CCHUNK);
    if (c0 >= c1) return;
    for (int b = tid; b < NSB; b += 256) cnt[b] = 0u;
    __syncthreads();
    unsigned dreg[CEPT];
    #pragma unroll
    for (int k = 0; k < CEPT; ++k) {
      int i = c0 + tid + k * 256;
      unsigned d = 0u;
      if (i < c1) {
        d = (unsigned)eidx[E + i];
        atomicAdd(&cnt[d >> SBSH], 1u);
      }
      dreg[k] = d;
    }
    __syncthreads();
    for (int b = tid; b < NSB; b += 256) {
      unsigned c = cnt[b];
      base[b] = c ? atomicAdd(&gsb[b], c) : 0u;
      cnt[b] = 0u;
    }
    __syncthreads();
    #pragma unroll
    for (int k = 0; k < CEPT; ++k) {
      int i = c0 + tid + k * 256;
      if (i < c1) {
        unsigned d = dreg[k];
        unsigned b = d >> SBSH;
        unsigned slot = base[b] + atomicAdd(&cnt[b], 1u);
        if (slot < CCAP)
          csb[(size_t)b * CCAP + slot] =
              make_int2((eidx[i] << SBSH) | (int)(d & (SBN - 1)), __float_as_int(ew[i]));
      }
    }
    return;
  }
  // ---------------- MFMA GEMM (both mats; stage x once) ----------------
  int B0 = ((int)blockIdx.x - NC) * 64;
  for (int i = tid; i < 64 * 32; i += 256) {
    int r = i >> 5, c4 = (i & 31) * 4;
    ushort4 o = {0, 0, 0, 0};
    if (B0 + r < n) {
      float4 v = *(const float4*)(x + (size_t)(B0 + r) * 128 + c4);
      o = make_ushort4(f2bf(v.x), f2bf(v.y), f2bf(v.z), f2bf(v.w));
    }
    *(ushort4*)&xs[r][c4] = o;
  }
  int wv = tid >> 6, lane = tid & 63;
  int l15 = lane & 15, g = lane >> 4;
  int R0 = wv * 16;
  int row = B0 + R0 + l15;
  for (int mat = 0; mat < 2; ++mat) {
    __syncthreads();
    for (int i = tid; i < 128 * 32; i += 256) {
      int c = i >> 5, k4 = (i & 31) * 4;
      *(ushort4*)&Wt[c][k4] = *(const ushort4*)(WtB + (size_t)mat * 16384 + c * 128 + k4);
    }
    __syncthreads();
    f32x4 acc[8];
    #pragma unroll
    for (int t = 0; t < 8; ++t) acc[t] = {0.f, 0.f, 0.f, 0.f};
    #pragma unroll
    for (int kc = 0; kc < 4; ++kc) {
      int k0 = kc * 32 + g * 8;
      short8v b = *(const short8v*)&xs[R0 + l15][k0];
      #pragma unroll
      for (int t = 0; t < 8; ++t) {
        short8v a = *(const short8v*)&Wt[t * 16 + l15][k0];
        acc[t] = __builtin_amdgcn_mfma_f32_16x16x32_bf16(a, b, acc[t], 0, 0, 0);
      }
    }
    const float* bias = mat ? br : bl;
    unsigned short* yp = mat ? xrb : xlb;
    float* qdst = mat ? qr : ql;
    float qp[4] = {0.f, 0.f, 0.f, 0.f};
    if (row < n) {
      const float s06 = 0.6f * LOG2E;
      #pragma unroll
      for (int t = 0; t < 8; ++t) {
        int c0 = t * 16 + g * 4;
        float4 bv = *(const float4*)(bias + c0);
        float4 av = *(const float4*)(att + c0);
        ushort4 o = {f2bf(acc[t][0] + bv.x), f2bf(acc[t][1] + bv.y),
                     f2bf(acc[t][2] + bv.z), f2bf(acc[t][3] + bv.w)};
        *(ushort4*)(yp + (size_t)row * 128 + c0) = o;
        float dot = av.x * bf2f(o.x) + av.y * bf2f(o.y)
                  + av.z * bf2f(o.z) + av.w * bf2f(o.w);
        qp[t >> 1] += s06 * dot;
      }
    }
    #pragma unroll
    for (int h = 0; h < 4; ++h) {
      qp[h] += __shfl_xor(qp[h], 16);
      qp[h] += __shfl_xor(qp[h], 32);
    }
    if (row < n && g == 0)
      *(float4*)(qdst + (size_t)row * 4) = make_float4(qp[0], qp[1], qp[2], qp[3]);
  }
}

// ---- phase B: sliced split into 32 fine-bucket slabs (global reserve on fcnt) ----
__global__ __launch_bounds__(256) void k_fine(const unsigned* __restrict__ gsb,
    const int2* __restrict__ csb, int2* __restrict__ ebkt,
    unsigned* __restrict__ fcnt, int NB) {
  __shared__ unsigned cnt[32];
  __shared__ unsigned base[32];
  int sb = blockIdx.x / FSLICE;
  int sl = blockIdx.x % FSLICE;
  int ne = min((int)gsb[sb], CCAP);
  int chunk = (ne + FSLICE - 1) / FSLICE;
  int i0 = sl * chunk, i1 = min(ne, i0 + chunk);
  if (i0 >= i1) return;
  const int2* src = csb + (size_t)sb * CCAP;
  if (threadIdx.x < 32) cnt[threadIdx.x] = 0u;
  __syncthreads();
  for (int i = i0 + threadIdx.x; i < i1; i += 256)
    atomicAdd(&cnt[(src[i].x >> 4) & 31], 1u);
  __syncthreads();
  if (threadIdx.x < 32) {
    unsigned c = cnt[threadIdx.x];
    base[threadIdx.x] = c ? atomicAdd(&fcnt[sb * 32 + (int)threadIdx.x], c) : 0u;
    cnt[threadIdx.x] = 0u;
  }
  __syncthreads();
  for (int i = i0 + threadIdx.x; i < i1; i += 256) {
    int2 e = src[i];
    int fb = (e.x >> 4) & 31;
    unsigned slot = base[fb] + atomicAdd(&cnt[fb], 1u);
    if (slot < CAP) {
      int packed = ((e.x >> SBSH) << 4) | (e.x & 15);
      ebkt[(size_t)(sb * 32 + fb) * CAP + slot] = make_int2(packed, e.y);
    }
  }
}

// ---- fused: LDS counting-sort + softmax agg (1-deep prefetch, packed math) -------
__global__ __launch_bounds__(256) void k_agg(
    const unsigned* __restrict__ fcnt, const int2* __restrict__ ebkt,
    const unsigned short* __restrict__ xlb, const unsigned short* __restrict__ xrb,
    const float* __restrict__ ql, const float* __restrict__ qr,
    const float* __restrict__ qe, const float* __restrict__ We,
    const float* __restrict__ att, const float* __restrict__ bias,
    float* __restrict__ out, int n) {
  __shared__ int2 es[CAP];
  __shared__ unsigned rp[BNODES + 1];
  __shared__ unsigned cur[BNODES];
  __shared__ unsigned scnt[BNODES];
  int tid = threadIdx.x;
  int lane = tid & 63, wv = tid >> 6;
  int bkt = blockIdx.x;
  int ne = min((int)fcnt[bkt], CAP);
  const int2* srcp = ebkt + (size_t)bkt * CAP;
  if (tid < BNODES) scnt[tid] = 0u;
  __syncthreads();
  int2 er[EPT];
  #pragma unroll
  for (int k = 0; k < EPT; ++k) {
    int i = tid + k * 256;
    if (i < ne) {
      er[k] = srcp[i];
      atomicAdd(&scnt[er[k].x & (BNODES - 1)], 1u);
    }
  }
  __syncthreads();
  if (tid < 64) {
    unsigned s = (lane < BNODES) ? scnt[lane] : 0u;
    #pragma unroll
    for (int off = 1; off < BNODES; off <<= 1) {
      unsigned t = __shfl_up(s, off);
      if (lane >= off) s += t;
    }
    if (lane < BNODES) { rp[lane + 1] = s; cur[lane] = 0u; }
    if (lane == 0) rp[0] = 0u;
  }
  __syncthreads();
  #pragma unroll
  for (int k = 0; k < EPT; ++k) {
    int i = tid + k * 256;
    if (i < ne) {
      int dl = er[k].x & (BNODES - 1);
      unsigned slot = rp[dl] + atomicAdd(&cur[dl], 1u);
      es[slot] = make_int2(er[k].x >> BSH, er[k].y);
    }
  }
  __syncthreads();

  int g = lane >> 4;          // edge-group 0..3
  int l4 = lane & 15;         // channel-lane
  int h = l4 >> 2;            // head
  int ch0 = l4 * 8;
  f32x2 we2[4], at2[4];
  {
    const float s04 = 0.4f * LOG2E;
    #pragma unroll
    for (int p = 0; p < 4; ++p) {
      float2 w = *(const float2*)(We + ch0 + p * 2);
      float2 a = *(const float2*)(att + ch0 + p * 2);
      we2[p] = (f32x2){w.x, w.y};
      at2[p] = (f32x2){s04 * a.x, s04 * a.y};
    }
  }
  float qeh = qe[h];

  for (int dl = wv; dl < BNODES; dl += 4) {
    int d = (bkt << BSH) + dl;
    if (d >= n) break;
    int s0 = (int)rp[dl], s1 = (int)rp[dl + 1];
    uint4 xrq = *(const uint4*)(xrb + ((size_t)d << 7) + ch0);
    f32x2 xr2[4];
    xr2[0] = (f32x2){__uint_as_float(xrq.x << 16), __uint_as_float(xrq.x & 0xFFFF0000u)};
    xr2[1] = (f32x2){__uint_as_float(xrq.y << 16), __uint_as_float(xrq.y & 0xFFFF0000u)};
    xr2[2] = (f32x2){__uint_as_float(xrq.z << 16), __uint_as_float(xrq.z & 0xFFFF0000u)};
    xr2[3] = (f32x2){__uint_as_float(xrq.w << 16), __uint_as_float(xrq.w & 0xFFFF0000u)};
    float qrd = qr[(size_t)d * 4 + h];
    float den = 0.f, wmax = -INFINITY;
    f32x2 a2[4];
    a2[0] = a2[1] = a2[2] = a2[3] = (f32x2){0.f, 0.f};
    int idx = s0 + g;
    bool valid = idx < s1;
    int2 ev = make_int2(0, 0);
    uint4 xq = {0, 0, 0, 0};
    float qls = 0.f;
    if (valid) {
      ev = es[idx];
      xq = *(const uint4*)(xlb + ((size_t)ev.x << 7) + ch0);
      qls = ql[(size_t)ev.x * 4 + h];
    }
    for (int j = s0; j < s1; j += 4) {
      int idxn = j + 4 + g;
      bool vn = idxn < s1;
      int2 evn = ev; uint4 xqn = xq; float qln = qls;
      if (vn) {
        evn = es[idxn];
        xqn = *(const uint4*)(xlb + ((size_t)evn.x << 7) + ch0);
        qln = ql[(size_t)evn.x * 4 + h];
      }
      if (valid) {
        float w = __int_as_float(ev.y);
        wmax = fmaxf(wmax, w);
        f32x2 w2 = (f32x2){w, w};
        f32x2 x2[4];
        x2[0] = (f32x2){__uint_as_float(xq.x << 16), __uint_as_float(xq.x & 0xFFFF0000u)};
        x2[1] = (f32x2){__uint_as_float(xq.y << 16), __uint_as_float(xq.y & 0xFFFF0000u)};
        x2[2] = (f32x2){__uint_as_float(xq.z << 16), __uint_as_float(xq.z & 0xFFFF0000u)};
        x2[3] = (f32x2){__uint_as_float(xq.w << 16), __uint_as_float(xq.w & 0xFFFF0000u)};
        f32x2 nl2 = (f32x2){0.f, 0.f};
        #pragma unroll
        for (int p = 0; p < 4; ++p) {
          f32x2 t2 = __builtin_elementwise_fma(w2, we2[p], xr2[p]) + x2[p];
          nl2 = __builtin_elementwise_fma(at2[p], __builtin_elementwise_abs(t2), nl2);
        }
        float nl = nl2.x + nl2.y;
        nl += __shfl_xor(nl, 1);
        nl += __shfl_xor(nl, 2);
        float pe = __builtin_amdgcn_exp2f(qls + fmaf(w, qeh, qrd) + nl);
        den += pe;
        f32x2 pe2 = (f32x2){pe, pe};
        #pragma unroll
        for (int p = 0; p < 4; ++p)
          a2[p] = __builtin_elementwise_fma(pe2, x2[p], a2[p]);
      }
      ev = evn; xq = xqn; qls = qln; valid = vn;
    }
    #pragma unroll
    for (int mask = 16; mask <= 32; mask <<= 1) {
      den += __shfl_xor(den, mask);
      #pragma unroll
      for (int p = 0; p < 4; ++p) {
        a2[p].x += __shfl_xor(a2[p].x, mask);
        a2[p].y += __shfl_xor(a2[p].y, mask);
      }
      wmax = fmaxf(wmax, __shfl_xor(wmax, mask));
    }
    // self-loop: weight = max incoming edge weight (0 if none)
    {
      float wl = (wmax > -INFINITY) ? wmax : 0.f;
      uint4 xq2 = *(const uint4*)(xlb + ((size_t)d << 7) + ch0);
      f32x2 w2 = (f32x2){wl, wl};
      f32x2 x2[4];
      x2[0] = (f32x2){__uint_as_float(xq2.x << 16), __uint_as_float(xq2.x & 0xFFFF0000u)};
      x2[1] = (f32x2){__uint_as_float(xq2.y << 16), __uint_as_float(xq2.y & 0xFFFF0000u)};
      x2[2] = (f32x2){__uint_as_float(xq2.z << 16), __uint_as_float(xq2.z & 0xFFFF0000u)};
      x2[3] = (f32x2){__uint_as_float(xq2.w << 16), __uint_as_float(xq2.w & 0xFFFF0000u)};
      f32x2 nl2 = (f32x2){0.f, 0.f};
      #pragma unroll
      for (int p = 0; p < 4; ++p) {
        f32x2 t2 = __builtin_elementwise_fma(w2, we2[p], xr2[p]) + x2[p];
        nl2 = __builtin_elementwise_fma(at2[p], __builtin_elementwise_abs(t2), nl2);
      }
      float nl = nl2.x + nl2.y;
      nl += __shfl_xor(nl, 1);
      nl += __shfl_xor(nl, 2);
      float qld = ql[(size_t)d * 4 + h];
      float pe = __builtin_amdgcn_exp2f(qld + fmaf(wl, qeh, qrd) + nl);
      den += pe;
      f32x2 pe2 = (f32x2){pe, pe};
      #pragma unroll
      for (int p = 0; p < 4; ++p)
        a2[p] = __builtin_elementwise_fma(pe2, x2[p], a2[p]);
    }
    if (g == 0) {
      float r = 1.0f / den;
      float4 bvA = *(const float4*)(bias + ch0);
      float4 bvB = *(const float4*)(bias + ch0 + 4);
      float* op = out + (size_t)d * 128 + ch0;
      float4 oA = {a2[0].x * r + bvA.x, a2[0].y * r + bvA.y,
                   a2[1].x * r + bvA.z, a2[1].y * r + bvA.w};
      float4 oB = {a2[2].x * r + bvB.x, a2[2].y * r + bvB.y,
                   a2[3].x * r + bvB.z, a2[3].y * r + bvB.w};
      *(float4*)op = oA;
      *(float4*)(op + 4) = oB;
    }
  }
}

extern "C" void kernel_launch(void* const* d_in, const int* in_sizes, int n_in,
                              void* d_out, int out_size, void* d_ws, size_t ws_size,
                              hipStream_t stream) {
  const float* x     = (const float*)d_in[0];
  const int*   eidx  = (const int*)d_in[1];
  const float* ew_in = (const float*)d_in[2];
  const float* Wl    = (const float*)d_in[3];
  const float* bl    = (const float*)d_in[4];
  const float* Wr    = (const float*)d_in[5];
  const float* br    = (const float*)d_in[6];
  const float* We    = (const float*)d_in[7];
  const float* att   = (const float*)d_in[8];
  const float* bias  = (const float*)d_in[9];
  float* out = (float*)d_out;

  const int N = in_sizes[0] / 128;
  const int E = in_sizes[2];
  const int NB = (N + BNODES - 1) >> BSH;
  const int NSB = (N + SBN - 1) >> SBSH;

  char* ws = (char*)d_ws;
  size_t off = 0;
  auto alloc = [&](size_t bytes) {
    void* p = ws + off;
    off = (off + bytes + 255) & ~(size_t)255;
    return p;
  };
  // no overlay: coarse (csb) and gemm (xlb/xrb) run concurrently inside k_gc
  int2* ebkt = (int2*)alloc((size_t)NB * CAP * 8);           // 19.2 MB
  int2* csb  = (int2*)alloc((size_t)NSB * CCAP * 8);         // 14.1 MB
  unsigned short* xlb = (unsigned short*)alloc((size_t)N * 128 * 2);  // 12.8 MB
  unsigned short* xrb = (unsigned short*)alloc((size_t)N * 128 * 2);  // 12.8 MB
  unsigned short* WtB = (unsigned short*)alloc(2 * 16384 * 2);
  float* ql = (float*)alloc((size_t)N * 4 * 4);
  float* qr = (float*)alloc((size_t)N * 4 * 4);
  float* qe = (float*)alloc(4 * 4);
  unsigned* fcnt = (unsigned*)alloc((size_t)NB * 4);
  unsigned* gsb  = (unsigned*)alloc((size_t)NSB * 4);

  k_prep<<<2, 256, 0, stream>>>(Wl, Wr, We, att, WtB, qe, fcnt, NB, gsb, NSB);

  int NC = (E + CCHUNK - 1) / CCHUNK;
  int NG = (N + 63) / 64;
  k_gc<<<NC + NG, 256, 0, stream>>>(eidx, ew_in, gsb, csb, E, NSB, NC,
                                    x, WtB, att, bl, br, xlb, xrb, ql, qr, N);

  k_fine<<<NSB * FSLICE, 256, 0, stream>>>(gsb, csb, ebkt, fcnt, NB);

  k_agg<<<NB, 256, 0, stream>>>(fcnt, ebkt, xlb, xrb, ql, qr, qe, We, att, bias, out, N);
}